// Round 4
// baseline (404.106 us; speedup 1.0000x reference)
//
#include <hip/hip_runtime.h>
#include <hip/hip_bf16.h>
#include <math.h>

// ---------------------------------------------------------------------------
// JointWiseFeedForward: T=16 independent per-position FFNs.
//   x:[16384,2048] f32 -> reshape [16384,128,16]; h = einsum(bct,oct)->bot with
//   w1:[512,128,16]; gelu(exact erf; we use tanh-form, |err|<1e-3);
//   y = einsum with w2:[128,512,16]; out feature = o*16+t.
// Strategy: bf16 MFMA, 4 kernels:
//   k_packw: w1/w2 fp32 -> bf16 in MFMA-fragment order
//   k_xt:    x -> xt[t][row][c] bf16  (ds_read_b64_tr_b16 HW transpose)
//   k_ffn:   fused GEMM1->gelu->bpermute->GEMM2, yt bf16 in-place
//   k_out:   yt -> out fp32           (LDS-free gather, coalesced loads)
// R7 (this round): R6 ran but absmax 3.2 — tr-read ADDRESS pattern was wrong.
//   True semantics (unique model consistent with m162's layout AND the
//   uniform-addr measurement): lane addr A reads column (A>>3)&15 of the
//   4x16 bf16 subtile at block A&~127, rows at +32B. So canonical usage is
//   NATURAL addressing A = base + 8*l (like a linear ds_read_b64); my old
//   A = base + 2*(l&15) + 128*(l>>4) gave column i>>2 (lanes 0-3 all col 0:
//   duplicated t-columns -> O(1) errors, and 2B-misaligned b64 addrs).
//   Fix is ONE line: base = lds_off(ls) + wv*8192 + l*8. Delivered layout
//   (c=chunk*16+4g+j, t=i) unchanged -> stores unchanged. Rest identical.
// ---------------------------------------------------------------------------

typedef __attribute__((ext_vector_type(8))) short bf16x8;
typedef __attribute__((ext_vector_type(4))) float f32x4;

#define MFMA16(a,b,c) __builtin_amdgcn_mfma_f32_16x16x32_bf16((a),(b),(c),0,0,0)

#define N_ROWS   16384
#define XT_PLANE (16384*128)     // elems per t-plane in xt/yt
#define W_TSTR   65536           // packed-weight elems per t  (4*8*4*64*8)
#define W_JSTR   16384           // packed-weight elems per jc chunk (8*4*64*8)

static __device__ __forceinline__ unsigned short f2bf(float f){
  union{float f; unsigned u;} v; v.f = f;
  return (unsigned short)((v.u + 0x7FFFu + ((v.u>>16)&1u))>>16);   // RNE
}
// packed RNE f32x2 -> bf16x2 via HW instruction (D.lo=cvt(lo), D.hi=cvt(hi))
static __device__ __forceinline__ unsigned cvtpk(float lo, float hi){
  unsigned r;
  asm("v_cvt_pk_bf16_f32 %0, %1, %2" : "=v"(r) : "v"(lo), "v"(hi));
  return r;
}
// bf16 (lo/hi half of u32) -> f32, 1 VALU op each
static __device__ __forceinline__ float bflo(unsigned u){
  union{unsigned x; float f;} c; c.x = u<<16; return c.f;
}
static __device__ __forceinline__ float bfhi(unsigned u){
  union{unsigned x; float f;} c; c.x = u & 0xffff0000u; return c.f;
}
// gelu(x) = x * sigmoid(1.5957691x + 0.0713548x^3)  (tanh form)
static __device__ __forceinline__ float gelu_fast(float x){
  float x2 = x*x;
  float m  = x*(-1.5957691216f - 0.0713548163f*x2);
  float e  = __expf(m);
  return x*__builtin_amdgcn_rcpf(1.0f + e);
}

typedef __attribute__((address_space(1))) const unsigned int gas_u32;
typedef __attribute__((address_space(3))) unsigned int las_u32;
static __device__ __forceinline__ void gload16(const void* g, void* l){
  __builtin_amdgcn_global_load_lds((gas_u32*)g, (las_u32*)l, 16, 0, 0);
}
// LDS byte-offset of a shared-memory pointer (addrspace(3) pointers are the
// raw 32-bit LDS offset; generic pointers are flat-aperture and must NOT be
// truncated).
static __device__ __forceinline__ unsigned lds_off(const void* p){
  return (unsigned)(size_t)(const __attribute__((address_space(3))) void*)p;
}

// ---------------- weight pack ------------------------------------------------
__global__ __launch_bounds__(256) void k_packw(const float* __restrict__ w1,
                                               const float* __restrict__ w2,
                                               unsigned short* __restrict__ w1p,
                                               unsigned short* __restrict__ w2p){
  int g = blockIdx.x*256 + threadIdx.x;           // 0..262143
  bool is1 = (g < 131072);
  int gg = is1 ? g : (g - 131072);
  int l  = gg & 63, q = (l>>4), i = l & 15;
  int ks = (gg>>6)&3, m8 = (gg>>8)&7, jc = (gg>>11)&3, t = (gg>>13)&15;
  union { unsigned short s[8]; bf16x8 v; } u;
  if (is1){
    int o  = jc*128 + m8*16 + i;
    int c0 = ks*32 + q*8;
    #pragma unroll
    for (int j=0;j<8;++j) u.s[j] = f2bf(w1[(o*128 + c0 + j)*16 + t]);
    *(bf16x8*)(w1p + (size_t)gg*8) = u.v;
  } else {
    int o2  = m8*16 + i;
    int cf0 = jc*128 + ks*32 + q*8;
    #pragma unroll
    for (int j=0;j<8;++j) u.s[j] = f2bf(w2[(o2*512 + cf0 + j)*16 + t]);
    *(bf16x8*)(w2p + (size_t)gg*8) = u.v;
  }
}

// ---------------- x transpose: x[r][c*16+t] -> xt[t][r][c] (bf16) -----------
// linear-LDS + ds_read_b64_tr_b16. Per row r the bf16 row is a [128 c][16 t]
// row-major matrix = 32 contiguous 4x16 subtiles (128B each).
// Phase 1: float4 loads, cvtpk, b64 linear LDS writes (conflict-free).
// Phase 2: NATURAL per-lane addr base+8*l; group g reads subtile at
//   +128g within the 512B window; offset rr*4096+chunk*512 walks windows.
//   Lane(g=l>>4,i=l&15) elem j = [c=chunk*16+4g+j][t=i] -> b64 global store.
#define TRRD(d, a, OFS) asm volatile("ds_read_b64_tr_b16 %0, %1 offset:" OFS \
                                     : "=v"(d) : "v"(a))
__global__ __launch_bounds__(256) void k_xt(const float* __restrict__ x,
                                            unsigned short* __restrict__ xt){
  __shared__ unsigned short ls[8*2048];           // [r][f] linear bf16, 32KB
  const int r0 = blockIdx.x*8;
  const int tid = threadIdx.x;
  #pragma unroll
  for (int it=0; it<16; ++it){
    int idx = it*256 + tid;                       // f4 index in 8x512
    int row = idx>>9, rem = idx&511;
    float4 v = *(const float4*)(x + (size_t)(r0+row)*2048 + rem*4);
    unsigned lo = cvtpk(v.x, v.y), hi = cvtpk(v.z, v.w);
    unsigned long long p = ((unsigned long long)hi<<32) | lo;
    *(unsigned long long*)(ls + row*2048 + rem*4) = p;
  }
  __syncthreads();
  const int wv = tid>>6, l = tid&63, g = l>>4, i = l&15;
  // R7 fix: natural addressing (column = (A>>3)&15 = lane&15, block = A&~127)
  unsigned base = lds_off(ls) + (unsigned)wv*8192u + (unsigned)l*8u;
  #pragma unroll
  for (int rr=0; rr<2; ++rr){
    unsigned long long d0,d1,d2,d3,d4,d5,d6,d7;
    if (rr==0){
      TRRD(d0, base, "0");    TRRD(d1, base, "512");
      TRRD(d2, base, "1024"); TRRD(d3, base, "1536");
      TRRD(d4, base, "2048"); TRRD(d5, base, "2560");
      TRRD(d6, base, "3072"); TRRD(d7, base, "3584");
    } else {
      TRRD(d0, base, "4096"); TRRD(d1, base, "4608");
      TRRD(d2, base, "5120"); TRRD(d3, base, "5632");
      TRRD(d4, base, "6144"); TRRD(d5, base, "6656");
      TRRD(d6, base, "7168"); TRRD(d7, base, "7680");
    }
    asm volatile("s_waitcnt lgkmcnt(0)" ::: "memory");
    __builtin_amdgcn_sched_barrier(0);
    unsigned short* xp = xt + (size_t)i*XT_PLANE
                       + (size_t)(r0 + 2*wv + rr)*128 + g*4;
    *(unsigned long long*)(xp + 0*16)  = d0;
    *(unsigned long long*)(xp + 1*16)  = d1;
    *(unsigned long long*)(xp + 2*16)  = d2;
    *(unsigned long long*)(xp + 3*16)  = d3;
    *(unsigned long long*)(xp + 4*16)  = d4;
    *(unsigned long long*)(xp + 5*16)  = d5;
    *(unsigned long long*)(xp + 6*16)  = d6;
    *(unsigned long long*)(xp + 7*16)  = d7;
  }
}

// ---------------- fused FFN GEMM (unchanged from R4) ------------------------
__global__ __launch_bounds__(256,2) void k_ffn(const unsigned short* __restrict__ xt,
                                               const unsigned short* __restrict__ w1p,
                                               const unsigned short* __restrict__ w2p,
                                               unsigned short* __restrict__ yt){
  __shared__ unsigned short ws[2*16384];          // 2 x (16KB w1-half + 16KB w2-half)
  const int bx = blockIdx.x;
  const int t = bx>>7, rt = bx&127, r0 = rt<<7;
  const int tid = threadIdx.x;
  const int wv = tid>>6, l = tid&63, q = l>>4, i = l&15;

  const unsigned short* w1t = w1p + (size_t)t*W_TSTR;
  const unsigned short* w2t = w2p + (size_t)t*W_TSTR;

  auto stage = [&](int hc, int buf){
    const int jc = hc>>1, half = hc&1;
    const unsigned short* w1c = w1t + jc*W_JSTR + half*8192;
    const unsigned short* w2c = w2t + jc*W_JSTR + half*1024;
    unsigned short* Wb = ws + buf*16384;
    #pragma unroll
    for (int c=0;c<8;++c){
      int k = wv*8 + c;                           // wave-uniform
      if (k < 16){
        gload16(w1c + k*512 + l*8, Wb + k*512 + l*8);
      } else {
        int f = k - 16;                           // f = nt2*2 + ks2'
        gload16(w2c + (f>>1)*2048 + (f&1)*512 + l*8, Wb + 8192 + f*512 + l*8);
      }
    }
  };

  stage(0, 0);

  bf16x8 xb[4][2];
  {
    const unsigned short* xp = xt + (size_t)t*XT_PLANE + (size_t)(r0 + wv*32)*128;
    #pragma unroll
    for (int ks=0; ks<4; ++ks){
      xb[ks][0] = *(const bf16x8*)(xp + (size_t)i*128 + ks*32 + q*8);
      xb[ks][1] = *(const bf16x8*)(xp + (size_t)(i+16)*128 + ks*32 + q*8);
    }
  }
  __syncthreads();                                // stage(0) landed

  f32x4 accY[2][8];
  #pragma unroll
  for (int a=0;a<2;++a)
    #pragma unroll
    for (int b=0;b<8;++b) accY[a][b] = (f32x4){0.f,0.f,0.f,0.f};

  const int idxA = ((q&1)*32 + i)*4;              // src lane*4 for frag j0..3
  const int idxB = idxA + 64;                     // +16 lanes for frag j4..7
  const int lo32 = (l < 32);                      // q>>1 == 0 ?

  int cur = 0;
  #pragma unroll 1
  for (int hc=0; hc<8; ++hc){                     // 8 half-chunks of 64 cff
    if (hc < 7) stage(hc+1, cur^1);               // issue loads BEFORE compute

    const unsigned short* W1 = ws + cur*16384;
    const unsigned short* W2 = W1 + 8192;

    f32x4 acc1[4][2];
    #pragma unroll
    for (int a=0;a<4;++a){ acc1[a][0]=(f32x4){0,0,0,0}; acc1[a][1]=(f32x4){0,0,0,0}; }
    #pragma unroll
    for (int ks=0; ks<4; ++ks){                   // K = cin = 128
      #pragma unroll
      for (int mt=0; mt<4; ++mt){
        bf16x8 af = *(const bf16x8*)(W1 + (mt*4+ks)*512 + l*8);
        acc1[mt][0] = MFMA16(af, xb[ks][0], acc1[mt][0]);
        acc1[mt][1] = MFMA16(af, xb[ks][1], acc1[mt][1]);
      }
    }

    unsigned pk[4][2][2];
    #pragma unroll
    for (int mt=0; mt<4; ++mt)
      #pragma unroll
      for (int nt=0; nt<2; ++nt){
        f32x4 v = acc1[mt][nt];
        pk[mt][nt][0] = cvtpk(gelu_fast(v.x), gelu_fast(v.y));
        pk[mt][nt][1] = cvtpk(gelu_fast(v.z), gelu_fast(v.w));
      }

    #pragma unroll
    for (int ks2=0; ks2<2; ++ks2){                // K = 64 local cff
      bf16x8 a2[2];
      #pragma unroll
      for (int nt=0; nt<2; ++nt){
        int pA0=(int)pk[2*ks2  ][nt][0], pA1=(int)pk[2*ks2  ][nt][1];
        int pB0=(int)pk[2*ks2+1][nt][0], pB1=(int)pk[2*ks2+1][nt][1];
        int a0 = __builtin_amdgcn_ds_bpermute(idxA, pA0);
        int b0 = __builtin_amdgcn_ds_bpermute(idxA, pB0);
        int a1 = __builtin_amdgcn_ds_bpermute(idxA, pA1);
        int b1 = __builtin_amdgcn_ds_bpermute(idxA, pB1);
        int a2r= __builtin_amdgcn_ds_bpermute(idxB, pA0);
        int b2 = __builtin_amdgcn_ds_bpermute(idxB, pB0);
        int a3 = __builtin_amdgcn_ds_bpermute(idxB, pA1);
        int b3 = __builtin_amdgcn_ds_bpermute(idxB, pB1);
        union{ int ii[4]; bf16x8 v; } u;
        u.ii[0] = lo32 ? a0 : b0;
        u.ii[1] = lo32 ? a1 : b1;
        u.ii[2] = lo32 ? a2r: b2;
        u.ii[3] = lo32 ? a3 : b3;
        a2[nt] = u.v;
      }
      #pragma unroll
      for (int nt2=0; nt2<8; ++nt2){
        bf16x8 bf = *(const bf16x8*)(W2 + (nt2*2+ks2)*512 + l*8);
        accY[0][nt2] = MFMA16(a2[0], bf, accY[0][nt2]);
        accY[1][nt2] = MFMA16(a2[1], bf, accY[1][nt2]);
      }
    }

    __syncthreads();        // drain stage loads (vmcnt0) + release ws[cur]
    cur ^= 1;
  }

  unsigned short* yp = yt + (size_t)t*XT_PLANE + (size_t)(r0 + wv*32)*128;
  #pragma unroll
  for (int mt2=0; mt2<2; ++mt2)
    #pragma unroll
    for (int nt2=0; nt2<8; ++nt2){
      f32x4 v = accY[mt2][nt2];
      unsigned p01 = cvtpk(v.x, v.y);
      unsigned p23 = cvtpk(v.z, v.w);
      int o = nt2*16 + i;
      int rowb = mt2*16 + q*4;
      yp[(rowb+0)*128 + o] = (unsigned short)(p01 & 0xffffu);
      yp[(rowb+1)*128 + o] = (unsigned short)(p01 >> 16);
      yp[(rowb+2)*128 + o] = (unsigned short)(p23 & 0xffffu);
      yp[(rowb+3)*128 + o] = (unsigned short)(p23 >> 16);
    }
}

// ---------------- output: yt[t][r][o] -> out[r][o*16+t] fp32 ----------------
// LDS-free. Thread unit (r, tq, og): 4 coalesced b128 loads from planes
// tq*4+j at the same [r][og*8] offset; element k of the 4 loads forms the
// f32x4 out[r][(og*8+k)*16 + tq*4 .. +3]. bf16->f32 = 1 shift/and each.
// 8 rows per block -> grid 2048.
__global__ __launch_bounds__(256) void k_out(const unsigned short* __restrict__ yt,
                                             float* __restrict__ out){
  const int r0 = blockIdx.x*8;
  const int tid = threadIdx.x;
  const int r = tid>>5, w = tid&31;
  const int og = w&15, tq0 = w>>4;
  #pragma unroll
  for (int it=0; it<2; ++it){
    int tq = tq0 + it*2;
    const unsigned short* yp = yt + (size_t)(tq*4)*XT_PLANE
                             + (size_t)(r0+r)*128 + og*8;
    union{ bf16x8 v; unsigned u[4]; } y0, y1, y2, y3;
    y0.v = *(const bf16x8*)(yp);
    y1.v = *(const bf16x8*)(yp + XT_PLANE);
    y2.v = *(const bf16x8*)(yp + 2*XT_PLANE);
    y3.v = *(const bf16x8*)(yp + 3*XT_PLANE);
    float* op = out + (size_t)(r0+r)*2048 + og*128 + tq*4;
    #pragma unroll
    for (int k=0;k<8;++k){
      unsigned w0 = y0.u[k>>1], w1 = y1.u[k>>1], w2 = y2.u[k>>1], w3 = y3.u[k>>1];
      f32x4 o4;
      if (k&1){ o4.x=bfhi(w0); o4.y=bfhi(w1); o4.z=bfhi(w2); o4.w=bfhi(w3); }
      else    { o4.x=bflo(w0); o4.y=bflo(w1); o4.z=bflo(w2); o4.w=bflo(w3); }
      *(f32x4*)(op + k*16) = o4;
    }
  }
}

// ---------------- exact fp32 fallback (if ws too small) ---------------------
__global__ __launch_bounds__(128) void k_naive(const float* __restrict__ x,
                                               const float* __restrict__ w1,
                                               const float* __restrict__ w2,
                                               float* __restrict__ out){
  int bid = blockIdx.x; int t = bid & 15; int row = bid >> 4;
  int tid = threadIdx.x;
  __shared__ float xsm[128]; __shared__ float hsm[512];
  xsm[tid] = x[(size_t)row*2048 + tid*16 + t];
  __syncthreads();
  for (int kk=0; kk<4; ++kk){
    int o = kk*128 + tid; float a = 0.f;
    for (int c=0;c<128;++c) a += xsm[c]*w1[(o*128+c)*16+t];
    hsm[o] = 0.5f*a*(1.0f+erff(a*0.70710678f));
  }
  __syncthreads();
  float a = 0.f;
  for (int cf=0; cf<512; ++cf) a += hsm[cf]*w2[(tid*512+cf)*16+t];
  out[(size_t)row*2048 + tid*16 + t] = a;
}

// ---------------------------------------------------------------------------
extern "C" void kernel_launch(void* const* d_in, const int* in_sizes, int n_in,
                              void* d_out, int out_size, void* d_ws, size_t ws_size,
                              hipStream_t stream){
  const float* x  = (const float*)d_in[0];
  const float* w1 = (const float*)d_in[1];
  const float* w2 = (const float*)d_in[2];
  float* out = (float*)d_out;

  const size_t NEEDED = 71303168ULL; // 67 MB xt/yt + 2+2 MB packed weights
  if (ws_size < NEEDED || d_ws == nullptr){
    k_naive<<<dim3(16384*16), dim3(128), 0, stream>>>(x, w1, w2, out);
    return;
  }
  unsigned short* xt  = (unsigned short*)d_ws;    // doubles as yt (in-place)
  unsigned short* w1p = xt + 33554432;
  unsigned short* w2p = w1p + 1048576;

  k_packw<<<dim3(1024), dim3(256), 0, stream>>>(w1, w2, w1p, w2p);
  k_xt  <<<dim3(2048), dim3(256), 0, stream>>>(x, xt);
  k_ffn <<<dim3(2048), dim3(256), 0, stream>>>(xt, w1p, w2p, xt);
  k_out <<<dim3(2048), dim3(256), 0, stream>>>(xt, out);   // 8 rows/block
}

// Round 5
// 369.648 us; speedup vs baseline: 1.0932x; 1.0932x over previous
//
#include <hip/hip_runtime.h>
#include <hip/hip_bf16.h>
#include <math.h>

// ---------------------------------------------------------------------------
// JointWiseFeedForward: T=16 independent per-position FFNs.
//   x:[16384,2048] f32 -> reshape [16384,128,16]; h = einsum(bct,oct)->bot with
//   w1:[512,128,16]; gelu; y = einsum with w2:[128,512,16]; out f = o*16+t.
// bf16 MFMA, 4 kernels: k_packw / k_xt / k_ffn / k_out.
// R8 (this round): R4 showed new transposes NET SLOWER (total 378->404,
//   k_ffn flat) — tr-read scattered global stores (16x32B segments/wave in
//   k_xt; 16B segments in k_out). Fixes:
//   1. k_xt: second LDS bounce after tr-read ([plane][row][c] stride 1032,
//      16B-aligned) -> 256B-coalesced b128 stores. All-vector.
//   2. k_out: redesign: coalesced plane loads -> LDS [r][og][t][o'] (t-stride
//      32B = tr subtile shape) -> tr-read gathers (o, 4t) -> f32x4 stores
//      tiling 1KB contiguous per wave. Perfect coalescing both sides.
//   3. k_ffn: occupancy 2->3 blocks/CU: quarter-chunk staging (2x16KB, 16
//      iters), launch_bounds(256,3); epilogue bounced through free ws ->
//      b128 yt stores (was 64 scalar b16 globals). xt/yt stay plane-major
//      in-place (row-major xt would break block-exclusive-slab invariant).
// ---------------------------------------------------------------------------

typedef __attribute__((ext_vector_type(8))) short bf16x8;
typedef __attribute__((ext_vector_type(4))) float f32x4;

#define MFMA16(a,b,c) __builtin_amdgcn_mfma_f32_16x16x32_bf16((a),(b),(c),0,0,0)

#define N_ROWS   16384
#define XT_PLANE (16384*128)     // elems per t-plane in xt/yt
#define W_TSTR   65536           // packed-weight elems per t
#define W_JSTR   16384           // packed-weight elems per jc chunk

static __device__ __forceinline__ unsigned short f2bf(float f){
  union{float f; unsigned u;} v; v.f = f;
  return (unsigned short)((v.u + 0x7FFFu + ((v.u>>16)&1u))>>16);   // RNE
}
static __device__ __forceinline__ unsigned cvtpk(float lo, float hi){
  unsigned r;
  asm("v_cvt_pk_bf16_f32 %0, %1, %2" : "=v"(r) : "v"(lo), "v"(hi));
  return r;
}
static __device__ __forceinline__ float bfs(unsigned short s){
  union{unsigned u; float f;} c; c.u = ((unsigned)s)<<16; return c.f;
}
// gelu(x) = x * sigmoid(1.5957691x + 0.0713548x^3)  (tanh form)
static __device__ __forceinline__ float gelu_fast(float x){
  float x2 = x*x;
  float m  = x*(-1.5957691216f - 0.0713548163f*x2);
  float e  = __expf(m);
  return x*__builtin_amdgcn_rcpf(1.0f + e);
}

typedef __attribute__((address_space(1))) const unsigned int gas_u32;
typedef __attribute__((address_space(3))) unsigned int las_u32;
static __device__ __forceinline__ void gload16(const void* g, void* l){
  __builtin_amdgcn_global_load_lds((gas_u32*)g, (las_u32*)l, 16, 0, 0);
}
static __device__ __forceinline__ unsigned lds_off(const void* p){
  return (unsigned)(size_t)(const __attribute__((address_space(3))) void*)p;
}

// ---------------- weight pack ------------------------------------------------
__global__ __launch_bounds__(256) void k_packw(const float* __restrict__ w1,
                                               const float* __restrict__ w2,
                                               unsigned short* __restrict__ w1p,
                                               unsigned short* __restrict__ w2p){
  int g = blockIdx.x*256 + threadIdx.x;           // 0..262143
  bool is1 = (g < 131072);
  int gg = is1 ? g : (g - 131072);
  int l  = gg & 63, q = (l>>4), i = l & 15;
  int ks = (gg>>6)&3, m8 = (gg>>8)&7, jc = (gg>>11)&3, t = (gg>>13)&15;
  union { unsigned short s[8]; bf16x8 v; } u;
  if (is1){
    int o  = jc*128 + m8*16 + i;
    int c0 = ks*32 + q*8;
    #pragma unroll
    for (int j=0;j<8;++j) u.s[j] = f2bf(w1[(o*128 + c0 + j)*16 + t]);
    *(bf16x8*)(w1p + (size_t)gg*8) = u.v;
  } else {
    int o2  = m8*16 + i;
    int cf0 = jc*128 + ks*32 + q*8;
    #pragma unroll
    for (int j=0;j<8;++j) u.s[j] = f2bf(w2[(o2*512 + cf0 + j)*16 + t]);
    *(bf16x8*)(w2p + (size_t)gg*8) = u.v;
  }
}

// ---------------- x transpose: x[r][c*16+t] -> xt[t][r][c] (bf16) -----------
// ph1: float4 loads, cvtpk, linear b64 LDS writes.
// ph2: tr-reads (natural addr base+8l): lane(g,i) gets [c=chunk*16+4g+j][t=i].
// ph3: bounce into LDS2 [plane i][row][c] stride 1032 (16B aligned).
// ph4: coalesced b128 reads + 256B-coalesced b128 global stores.
#define TRRD(d, a, OFS) asm volatile("ds_read_b64_tr_b16 %0, %1 offset:" OFS \
                                     : "=v"(d) : "v"(a))
__global__ __launch_bounds__(256) void k_xt(const float* __restrict__ x,
                                            unsigned short* __restrict__ xt){
  __shared__ unsigned short ls[16512];  // ph1/2: 8x2048; ph3/4: 16x1032
  const int r0 = blockIdx.x*8;
  const int tid = threadIdx.x;
  #pragma unroll
  for (int it=0; it<16; ++it){
    int idx = it*256 + tid;
    int row = idx>>9, rem = idx&511;
    float4 v = *(const float4*)(x + (size_t)(r0+row)*2048 + rem*4);
    unsigned lo = cvtpk(v.x, v.y), hi = cvtpk(v.z, v.w);
    unsigned long long p = ((unsigned long long)hi<<32) | lo;
    *(unsigned long long*)(ls + row*2048 + rem*4) = p;
  }
  __syncthreads();
  const int wv = tid>>6, l = tid&63, g = l>>4, i = l&15;
  unsigned base = lds_off(ls) + (unsigned)wv*8192u + (unsigned)l*8u;
  unsigned long long d[16];
  TRRD(d[0],  base, "0");    TRRD(d[1],  base, "512");
  TRRD(d[2],  base, "1024"); TRRD(d[3],  base, "1536");
  TRRD(d[4],  base, "2048"); TRRD(d[5],  base, "2560");
  TRRD(d[6],  base, "3072"); TRRD(d[7],  base, "3584");
  TRRD(d[8],  base, "4096"); TRRD(d[9],  base, "4608");
  TRRD(d[10], base, "5120"); TRRD(d[11], base, "5632");
  TRRD(d[12], base, "6144"); TRRD(d[13], base, "6656");
  TRRD(d[14], base, "7168"); TRRD(d[15], base, "7680");
  asm volatile("s_waitcnt lgkmcnt(0)" ::: "memory");
  __builtin_amdgcn_sched_barrier(0);
  __syncthreads();                                 // all tr-reads done -> reuse ls
  // ph3: d[rr*8+chunk] = row (r0+2wv+rr), plane i, c = chunk*16+4g..+3
  #pragma unroll
  for (int rr=0; rr<2; ++rr)
    #pragma unroll
    for (int ch=0; ch<8; ++ch)
      *(unsigned long long*)(ls + i*1032 + (2*wv+rr)*128 + ch*16 + g*4) = d[rr*8+ch];
  __syncthreads();
  // ph4: thread (p, cg): 8 rows of plane p, coalesced out
  const int p = tid>>4, cg = tid&15;
  #pragma unroll
  for (int row=0; row<8; ++row){
    bf16x8 v = *(const bf16x8*)(ls + p*1032 + row*128 + cg*8);
    *(bf16x8*)(xt + (size_t)p*XT_PLANE + (size_t)(r0+row)*128 + cg*8) = v;
  }
}

// ---------------- fused FFN GEMM --------------------------------------------
// block = (row-tile 128, t); 4 waves x 32 rows. Quarter-chunk pipeline:
// qc = jc*4+q4 covers 32 cff: stage 8KB w1-frags + 8KB w2-frags (double buf,
// 2x16KB = 32KB), 16 iters, 1 barrier each -> 3 blocks/CU (was 2).
// GEMM1 swapped (W1 A-frag LDS, x B-frag regs) -> gelu+cvtpk -> bpermute lane
// transform -> GEMM2 (H A-frag, W2 B-frag LDS). Epilogue: accY -> ws bounce
// (stride 132) -> b128 coalesced yt stores (in-place over xt, own slab).
__global__ __launch_bounds__(256,3) void k_ffn(const unsigned short* __restrict__ xt,
                                               const unsigned short* __restrict__ w1p,
                                               const unsigned short* __restrict__ w2p,
                                               unsigned short* __restrict__ yt){
  __shared__ unsigned short ws[16896];  // staging 2x8192; epilogue 4x4224
  const int bx = blockIdx.x;
  const int t = bx>>7, rt = bx&127, r0 = rt<<7;
  const int tid = threadIdx.x;
  const int wv = tid>>6, l = tid&63, q = l>>4, i = l&15;

  const unsigned short* w1t = w1p + (size_t)t*W_TSTR;
  const unsigned short* w2t = w2p + (size_t)t*W_TSTR;

  // stage quarter-chunk qc (jc=qc>>2, q4=qc&3): w1 frags (q4*2+m)*4+ks ->
  // slots m*4+ks; w2 frags nt2*4+q4 -> slots 8..15.
  auto stage = [&](int qc, int buf){
    const int jc = qc>>2, q4 = qc&3;
    const unsigned short* w1c = w1t + jc*W_JSTR;
    const unsigned short* w2c = w2t + jc*W_JSTR;
    unsigned short* Wb = ws + buf*8192;
    #pragma unroll
    for (int c=0;c<4;++c){
      int k = wv*4 + c;                           // wave-uniform 0..15
      if (k < 8){
        int m = k>>2, ks = k&3;
        gload16(w1c + ((q4*2+m)*4+ks)*512 + l*8, Wb + (m*4+ks)*512 + l*8);
      } else {
        int f = k - 8;                            // nt2
        gload16(w2c + (f*4+q4)*512 + l*8, Wb + 4096 + f*512 + l*8);
      }
    }
  };

  stage(0, 0);

  bf16x8 xb[4][2];
  {
    const unsigned short* xp = xt + (size_t)t*XT_PLANE + (size_t)(r0 + wv*32)*128;
    #pragma unroll
    for (int ks=0; ks<4; ++ks){
      xb[ks][0] = *(const bf16x8*)(xp + (size_t)i*128 + ks*32 + q*8);
      xb[ks][1] = *(const bf16x8*)(xp + (size_t)(i+16)*128 + ks*32 + q*8);
    }
  }
  __syncthreads();                                // stage(0) landed

  f32x4 accY[2][8];
  #pragma unroll
  for (int a=0;a<2;++a)
    #pragma unroll
    for (int b=0;b<8;++b) accY[a][b] = (f32x4){0.f,0.f,0.f,0.f};

  const int idxA = ((q&1)*32 + i)*4;
  const int idxB = idxA + 64;
  const int lo32 = (l < 32);                      // m = q>>1 selector

  int cur = 0;
  #pragma unroll 1
  for (int qc=0; qc<16; ++qc){                    // 16 quarter-chunks of 32 cff
    if (qc < 15) stage(qc+1, cur^1);

    const unsigned short* W1 = ws + cur*8192;
    const unsigned short* W2 = W1 + 4096;

    f32x4 acc1[2][2];
    #pragma unroll
    for (int a=0;a<2;++a){ acc1[a][0]=(f32x4){0,0,0,0}; acc1[a][1]=(f32x4){0,0,0,0}; }
    #pragma unroll
    for (int ks=0; ks<4; ++ks){
      #pragma unroll
      for (int m=0; m<2; ++m){
        bf16x8 af = *(const bf16x8*)(W1 + (m*4+ks)*512 + l*8);
        acc1[m][0] = MFMA16(af, xb[ks][0], acc1[m][0]);
        acc1[m][1] = MFMA16(af, xb[ks][1], acc1[m][1]);
      }
    }

    unsigned pk[2][2][2];
    #pragma unroll
    for (int m=0; m<2; ++m)
      #pragma unroll
      for (int nt=0; nt<2; ++nt){
        f32x4 v = acc1[m][nt];
        pk[m][nt][0] = cvtpk(gelu_fast(v.x), gelu_fast(v.y));
        pk[m][nt][1] = cvtpk(gelu_fast(v.z), gelu_fast(v.w));
      }

    // lane transform: target lane (q,i) needs H[row=nt*16+i][k=8q+j];
    // source tile m=q>>1 (lo32 select), src lane q_s=2(q&1)+(j>>2).
    bf16x8 a2[2];
    #pragma unroll
    for (int nt=0; nt<2; ++nt){
      int pA0=(int)pk[0][nt][0], pA1=(int)pk[0][nt][1];
      int pB0=(int)pk[1][nt][0], pB1=(int)pk[1][nt][1];
      int a0 = __builtin_amdgcn_ds_bpermute(idxA, pA0);
      int b0 = __builtin_amdgcn_ds_bpermute(idxA, pB0);
      int a1 = __builtin_amdgcn_ds_bpermute(idxA, pA1);
      int b1 = __builtin_amdgcn_ds_bpermute(idxA, pB1);
      int a2r= __builtin_amdgcn_ds_bpermute(idxB, pA0);
      int b2 = __builtin_amdgcn_ds_bpermute(idxB, pB0);
      int a3 = __builtin_amdgcn_ds_bpermute(idxB, pA1);
      int b3 = __builtin_amdgcn_ds_bpermute(idxB, pB1);
      union{ int ii[4]; bf16x8 v; } u;
      u.ii[0] = lo32 ? a0 : b0;
      u.ii[1] = lo32 ? a1 : b1;
      u.ii[2] = lo32 ? a2r: b2;
      u.ii[3] = lo32 ? a3 : b3;
      a2[nt] = u.v;
    }
    #pragma unroll
    for (int nt2=0; nt2<8; ++nt2){
      bf16x8 bf = *(const bf16x8*)(W2 + nt2*512 + l*8);
      accY[0][nt2] = MFMA16(a2[0], bf, accY[0][nt2]);
      accY[1][nt2] = MFMA16(a2[1], bf, accY[1][nt2]);
    }

    __syncthreads();
    cur ^= 1;
  }

  // epilogue: bounce accY through ws (per-wave 32x132 slab), b128 yt stores.
  unsigned short* wse = ws + wv*4224;
  #pragma unroll
  for (int mt2=0; mt2<2; ++mt2)
    #pragma unroll
    for (int nt2=0; nt2<8; ++nt2){
      f32x4 v = accY[mt2][nt2];
      unsigned p01 = cvtpk(v.x, v.y), p23 = cvtpk(v.z, v.w);
      int o = nt2*16 + i, rowb = mt2*16 + q*4;
      wse[(rowb+0)*132 + o] = (unsigned short)(p01 & 0xffffu);
      wse[(rowb+1)*132 + o] = (unsigned short)(p01 >> 16);
      wse[(rowb+2)*132 + o] = (unsigned short)(p23 & 0xffffu);
      wse[(rowb+3)*132 + o] = (unsigned short)(p23 >> 16);
    }
  asm volatile("s_waitcnt lgkmcnt(0)" ::: "memory");
  __builtin_amdgcn_sched_barrier(0);
  unsigned short* yp = yt + (size_t)t*XT_PLANE + (size_t)(r0 + wv*32)*128;
  #pragma unroll
  for (int u=0; u<8; ++u){
    int row = u*4 + (l>>4);
    int o8  = (l&15)*8;
    bf16x8 vv = *(const bf16x8*)(wse + row*132 + o8);
    *(bf16x8*)(yp + row*128 + o8) = vv;
  }
}

// ---------------- output: yt[t][r][o] -> out[r][o*16+t] fp32 ----------------
// ph1: coalesced b128 plane loads -> LDS [r:8][og:8][t:16][o':16] (t-stride
//   32B = tr subtile row). ph2: tr-read at base r*4096+og*512+l*8 gives
//   lane(g,i): (o=og*16+i, t=4g+j) -> f32x4 store; lanes tile 1KB contiguous.
__global__ __launch_bounds__(256) void k_out(const unsigned short* __restrict__ yt,
                                             float* __restrict__ out){
  __shared__ unsigned short ls[16384];            // 8r x 8og x 16t x 16o'
  const int r0 = blockIdx.x*8;
  const int tid = threadIdx.x;
  { // ph1
    const int tp = tid>>4, cg = tid&15;
    const int og = cg>>1, o0 = (cg&1)*8;
    #pragma unroll
    for (int r=0; r<8; ++r){
      bf16x8 v = *(const bf16x8*)(yt + (size_t)tp*XT_PLANE
                                     + (size_t)(r0+r)*128 + cg*8);
      *(bf16x8*)(ls + r*2048 + og*256 + tp*16 + o0) = v;
    }
  }
  __syncthreads();
  const int wv = tid>>6, l = tid&63, g = l>>4, i = l&15;
  unsigned base = lds_off(ls) + (unsigned)wv*8192u + (unsigned)l*8u;
  #pragma unroll
  for (int rr=0; rr<2; ++rr){
    unsigned long long d0,d1,d2,d3,d4,d5,d6,d7;
    if (rr==0){
      TRRD(d0, base, "0");    TRRD(d1, base, "512");
      TRRD(d2, base, "1024"); TRRD(d3, base, "1536");
      TRRD(d4, base, "2048"); TRRD(d5, base, "2560");
      TRRD(d6, base, "3072"); TRRD(d7, base, "3584");
    } else {
      TRRD(d0, base, "4096"); TRRD(d1, base, "4608");
      TRRD(d2, base, "5120"); TRRD(d3, base, "5632");
      TRRD(d4, base, "6144"); TRRD(d5, base, "6656");
      TRRD(d6, base, "7168"); TRRD(d7, base, "7680");
    }
    asm volatile("s_waitcnt lgkmcnt(0)" ::: "memory");
    __builtin_amdgcn_sched_barrier(0);
    float* op = out + (size_t)(r0 + 2*wv + rr)*2048 + i*16 + g*4;
    unsigned long long dd[8] = {d0,d1,d2,d3,d4,d5,d6,d7};
    #pragma unroll
    for (int og=0; og<8; ++og){
      union{ unsigned long long u; unsigned short s[4]; } w; w.u = dd[og];
      f32x4 o4;
      o4.x = bfs(w.s[0]); o4.y = bfs(w.s[1]);
      o4.z = bfs(w.s[2]); o4.w = bfs(w.s[3]);
      *(f32x4*)(op + og*256) = o4;
    }
  }
}

// ---------------- exact fp32 fallback (if ws too small) ---------------------
__global__ __launch_bounds__(128) void k_naive(const float* __restrict__ x,
                                               const float* __restrict__ w1,
                                               const float* __restrict__ w2,
                                               float* __restrict__ out){
  int bid = blockIdx.x; int t = bid & 15; int row = bid >> 4;
  int tid = threadIdx.x;
  __shared__ float xsm[128]; __shared__ float hsm[512];
  xsm[tid] = x[(size_t)row*2048 + tid*16 + t];
  __syncthreads();
  for (int kk=0; kk<4; ++kk){
    int o = kk*128 + tid; float a = 0.f;
    for (int c=0;c<128;++c) a += xsm[c]*w1[(o*128+c)*16+t];
    hsm[o] = 0.5f*a*(1.0f+erff(a*0.70710678f));
  }
  __syncthreads();
  float a = 0.f;
  for (int cf=0; cf<512; ++cf) a += hsm[cf]*w2[(tid*512+cf)*16+t];
  out[(size_t)row*2048 + tid*16 + t] = a;
}

// ---------------------------------------------------------------------------
extern "C" void kernel_launch(void* const* d_in, const int* in_sizes, int n_in,
                              void* d_out, int out_size, void* d_ws, size_t ws_size,
                              hipStream_t stream){
  const float* x  = (const float*)d_in[0];
  const float* w1 = (const float*)d_in[1];
  const float* w2 = (const float*)d_in[2];
  float* out = (float*)d_out;

  const size_t NEEDED = 71303168ULL; // 67 MB xt/yt + 2+2 MB packed weights
  if (ws_size < NEEDED || d_ws == nullptr){
    k_naive<<<dim3(16384*16), dim3(128), 0, stream>>>(x, w1, w2, out);
    return;
  }
  unsigned short* xt  = (unsigned short*)d_ws;    // doubles as yt (in-place)
  unsigned short* w1p = xt + 33554432;
  unsigned short* w2p = w1p + 1048576;

  k_packw<<<dim3(1024), dim3(256), 0, stream>>>(w1, w2, w1p, w2p);
  k_xt  <<<dim3(2048), dim3(256), 0, stream>>>(x, xt);
  k_ffn <<<dim3(2048), dim3(256), 0, stream>>>(xt, w1p, w2p, xt);
  k_out <<<dim3(2048), dim3(256), 0, stream>>>(xt, out);
}

// Round 6
// 368.471 us; speedup vs baseline: 1.0967x; 1.0032x over previous
//
#include <hip/hip_runtime.h>
#include <hip/hip_bf16.h>
#include <math.h>

// ---------------------------------------------------------------------------
// JointWiseFeedForward: T=16 independent per-position FFNs.
//   x:[16384,2048] f32 -> reshape [16384,128,16]; h = einsum(bct,oct)->bot with
//   w1:[512,128,16]; gelu; y = einsum with w2:[128,512,16]; out f = o*16+t.
// bf16 MFMA, 4 kernels: k_packw / k_xt / k_ffn / k_out.
// R9 (this round): k_ffn flat at ~117us across occupancy 20->28% => not
//   occupancy-bound; it's the per-iter __syncthreads barrier DRAIN
//   (s_waitcnt vmcnt(0)) serializing each stage's L2 latency (~200-500cy)
//   against ~350cy of compute, every one of 16 iters. Fix = T3/T4:
//   raw s_barrier + COUNTED vmcnt (never 0 in loop), 3-buffer staging
//   (48KB, still 3 blocks/CU), prefetch distance 2: iter qc stages qc+2,
//   waits vmcnt(8) (outstanding <= stages qc,qc+1,qc+2 = 12 -> waiting to 8
//   lands stage qc). Tail: vmcnt(4) @qc=14, vmcnt(0) @qc=15. sched_barrier(0)
//   fences after each wait/barrier (rule #18). T5 setprio around MFMA.
//   k_xt / k_out / k_packw byte-identical to R5 for attribution.
// ---------------------------------------------------------------------------

typedef __attribute__((ext_vector_type(8))) short bf16x8;
typedef __attribute__((ext_vector_type(4))) float f32x4;

#define MFMA16(a,b,c) __builtin_amdgcn_mfma_f32_16x16x32_bf16((a),(b),(c),0,0,0)

#define N_ROWS   16384
#define XT_PLANE (16384*128)     // elems per t-plane in xt/yt
#define W_TSTR   65536           // packed-weight elems per t
#define W_JSTR   16384           // packed-weight elems per jc chunk

static __device__ __forceinline__ unsigned short f2bf(float f){
  union{float f; unsigned u;} v; v.f = f;
  return (unsigned short)((v.u + 0x7FFFu + ((v.u>>16)&1u))>>16);   // RNE
}
static __device__ __forceinline__ unsigned cvtpk(float lo, float hi){
  unsigned r;
  asm("v_cvt_pk_bf16_f32 %0, %1, %2" : "=v"(r) : "v"(lo), "v"(hi));
  return r;
}
static __device__ __forceinline__ float bfs(unsigned short s){
  union{unsigned u; float f;} c; c.u = ((unsigned)s)<<16; return c.f;
}
// gelu(x) = x * sigmoid(1.5957691x + 0.0713548x^3)  (tanh form)
static __device__ __forceinline__ float gelu_fast(float x){
  float x2 = x*x;
  float m  = x*(-1.5957691216f - 0.0713548163f*x2);
  float e  = __expf(m);
  return x*__builtin_amdgcn_rcpf(1.0f + e);
}

typedef __attribute__((address_space(1))) const unsigned int gas_u32;
typedef __attribute__((address_space(3))) unsigned int las_u32;
static __device__ __forceinline__ void gload16(const void* g, void* l){
  __builtin_amdgcn_global_load_lds((gas_u32*)g, (las_u32*)l, 16, 0, 0);
}
static __device__ __forceinline__ unsigned lds_off(const void* p){
  return (unsigned)(size_t)(const __attribute__((address_space(3))) void*)p;
}

// ---------------- weight pack ------------------------------------------------
__global__ __launch_bounds__(256) void k_packw(const float* __restrict__ w1,
                                               const float* __restrict__ w2,
                                               unsigned short* __restrict__ w1p,
                                               unsigned short* __restrict__ w2p){
  int g = blockIdx.x*256 + threadIdx.x;           // 0..262143
  bool is1 = (g < 131072);
  int gg = is1 ? g : (g - 131072);
  int l  = gg & 63, q = (l>>4), i = l & 15;
  int ks = (gg>>6)&3, m8 = (gg>>8)&7, jc = (gg>>11)&3, t = (gg>>13)&15;
  union { unsigned short s[8]; bf16x8 v; } u;
  if (is1){
    int o  = jc*128 + m8*16 + i;
    int c0 = ks*32 + q*8;
    #pragma unroll
    for (int j=0;j<8;++j) u.s[j] = f2bf(w1[(o*128 + c0 + j)*16 + t]);
    *(bf16x8*)(w1p + (size_t)gg*8) = u.v;
  } else {
    int o2  = m8*16 + i;
    int cf0 = jc*128 + ks*32 + q*8;
    #pragma unroll
    for (int j=0;j<8;++j) u.s[j] = f2bf(w2[(o2*512 + cf0 + j)*16 + t]);
    *(bf16x8*)(w2p + (size_t)gg*8) = u.v;
  }
}

// ---------------- x transpose: x[r][c*16+t] -> xt[t][r][c] (bf16) -----------
#define TRRD(d, a, OFS) asm volatile("ds_read_b64_tr_b16 %0, %1 offset:" OFS \
                                     : "=v"(d) : "v"(a))
__global__ __launch_bounds__(256) void k_xt(const float* __restrict__ x,
                                            unsigned short* __restrict__ xt){
  __shared__ unsigned short ls[16512];  // ph1/2: 8x2048; ph3/4: 16x1032
  const int r0 = blockIdx.x*8;
  const int tid = threadIdx.x;
  #pragma unroll
  for (int it=0; it<16; ++it){
    int idx = it*256 + tid;
    int row = idx>>9, rem = idx&511;
    float4 v = *(const float4*)(x + (size_t)(r0+row)*2048 + rem*4);
    unsigned lo = cvtpk(v.x, v.y), hi = cvtpk(v.z, v.w);
    unsigned long long p = ((unsigned long long)hi<<32) | lo;
    *(unsigned long long*)(ls + row*2048 + rem*4) = p;
  }
  __syncthreads();
  const int wv = tid>>6, l = tid&63, g = l>>4, i = l&15;
  unsigned base = lds_off(ls) + (unsigned)wv*8192u + (unsigned)l*8u;
  unsigned long long d[16];
  TRRD(d[0],  base, "0");    TRRD(d[1],  base, "512");
  TRRD(d[2],  base, "1024"); TRRD(d[3],  base, "1536");
  TRRD(d[4],  base, "2048"); TRRD(d[5],  base, "2560");
  TRRD(d[6],  base, "3072"); TRRD(d[7],  base, "3584");
  TRRD(d[8],  base, "4096"); TRRD(d[9],  base, "4608");
  TRRD(d[10], base, "5120"); TRRD(d[11], base, "5632");
  TRRD(d[12], base, "6144"); TRRD(d[13], base, "6656");
  TRRD(d[14], base, "7168"); TRRD(d[15], base, "7680");
  asm volatile("s_waitcnt lgkmcnt(0)" ::: "memory");
  __builtin_amdgcn_sched_barrier(0);
  __syncthreads();                                 // all tr-reads done -> reuse ls
  #pragma unroll
  for (int rr=0; rr<2; ++rr)
    #pragma unroll
    for (int ch=0; ch<8; ++ch)
      *(unsigned long long*)(ls + i*1032 + (2*wv+rr)*128 + ch*16 + g*4) = d[rr*8+ch];
  __syncthreads();
  const int p = tid>>4, cg = tid&15;
  #pragma unroll
  for (int row=0; row<8; ++row){
    bf16x8 v = *(const bf16x8*)(ls + p*1032 + row*128 + cg*8);
    *(bf16x8*)(xt + (size_t)p*XT_PLANE + (size_t)(r0+row)*128 + cg*8) = v;
  }
}

// ---------------- fused FFN GEMM --------------------------------------------
// block = (row-tile 128, t); 4 waves x 32 rows. 16 quarter-chunks of 32 cff.
// R9 pipeline: 3 staging buffers (3x16KB), prefetch distance 2, counted
// vmcnt (8/4/0), raw s_barrier, setprio around MFMA clusters.
__global__ __launch_bounds__(256,3) void k_ffn(const unsigned short* __restrict__ xt,
                                               const unsigned short* __restrict__ w1p,
                                               const unsigned short* __restrict__ w2p,
                                               unsigned short* __restrict__ yt){
  __shared__ unsigned short ws[24576];  // 3 x 8192-elem staging; epi 4x4224
  const int bx = blockIdx.x;
  const int t = bx>>7, rt = bx&127, r0 = rt<<7;
  const int tid = threadIdx.x;
  const int wv = tid>>6, l = tid&63, q = l>>4, i = l&15;

  const unsigned short* w1t = w1p + (size_t)t*W_TSTR;
  const unsigned short* w2t = w2p + (size_t)t*W_TSTR;

  // stage quarter-chunk qc (jc=qc>>2, q4=qc&3) into buffer buf: 4 gload16/wave
  auto stage = [&](int qc, int buf){
    const int jc = qc>>2, q4 = qc&3;
    const unsigned short* w1c = w1t + jc*W_JSTR;
    const unsigned short* w2c = w2t + jc*W_JSTR;
    unsigned short* Wb = ws + buf*8192;
    #pragma unroll
    for (int c=0;c<4;++c){
      int k = wv*4 + c;                           // wave-uniform 0..15
      if (k < 8){
        int m = k>>2, ks = k&3;
        gload16(w1c + ((q4*2+m)*4+ks)*512 + l*8, Wb + (m*4+ks)*512 + l*8);
      } else {
        int f = k - 8;                            // nt2
        gload16(w2c + (f*4+q4)*512 + l*8, Wb + 4096 + f*512 + l*8);
      }
    }
  };

  stage(0, 0);
  stage(1, 1);

  bf16x8 xb[4][2];
  {
    const unsigned short* xp = xt + (size_t)t*XT_PLANE + (size_t)(r0 + wv*32)*128;
    #pragma unroll
    for (int ks=0; ks<4; ++ks){
      xb[ks][0] = *(const bf16x8*)(xp + (size_t)i*128 + ks*32 + q*8);
      xb[ks][1] = *(const bf16x8*)(xp + (size_t)(i+16)*128 + ks*32 + q*8);
    }
  }

  f32x4 accY[2][8];
  #pragma unroll
  for (int a=0;a<2;++a)
    #pragma unroll
    for (int b=0;b<8;++b) accY[a][b] = (f32x4){0.f,0.f,0.f,0.f};

  const int idxA = ((q&1)*32 + i)*4;
  const int idxB = idxA + 64;
  const int lo32 = (l < 32);                      // m = q>>1 selector

  int bc = 0, bs = 2;                             // consume qc%3, stage (qc+2)%3
  #pragma unroll 1
  for (int qc=0; qc<16; ++qc){
    if (qc < 14) stage(qc+2, bs);
    // counted wait: outstanding <= stages {qc,qc+1,qc+2} = 12; waiting to 8
    // lands stage(qc). Tail: 4 @qc=14 (s14,s15 in flight), 0 @qc=15.
    if (qc < 14)       asm volatile("s_waitcnt vmcnt(8)" ::: "memory");
    else if (qc == 14) asm volatile("s_waitcnt vmcnt(4)" ::: "memory");
    else               asm volatile("s_waitcnt vmcnt(0)" ::: "memory");
    __builtin_amdgcn_sched_barrier(0);
    __builtin_amdgcn_s_barrier();
    __builtin_amdgcn_sched_barrier(0);

    const unsigned short* W1 = ws + bc*8192;
    const unsigned short* W2 = W1 + 4096;

    f32x4 acc1[2][2];
    #pragma unroll
    for (int a=0;a<2;++a){ acc1[a][0]=(f32x4){0,0,0,0}; acc1[a][1]=(f32x4){0,0,0,0}; }
    __builtin_amdgcn_s_setprio(1);
    #pragma unroll
    for (int ks=0; ks<4; ++ks){
      #pragma unroll
      for (int m=0; m<2; ++m){
        bf16x8 af = *(const bf16x8*)(W1 + (m*4+ks)*512 + l*8);
        acc1[m][0] = MFMA16(af, xb[ks][0], acc1[m][0]);
        acc1[m][1] = MFMA16(af, xb[ks][1], acc1[m][1]);
      }
    }
    __builtin_amdgcn_s_setprio(0);

    unsigned pk[2][2][2];
    #pragma unroll
    for (int m=0; m<2; ++m)
      #pragma unroll
      for (int nt=0; nt<2; ++nt){
        f32x4 v = acc1[m][nt];
        pk[m][nt][0] = cvtpk(gelu_fast(v.x), gelu_fast(v.y));
        pk[m][nt][1] = cvtpk(gelu_fast(v.z), gelu_fast(v.w));
      }

    bf16x8 a2[2];
    #pragma unroll
    for (int nt=0; nt<2; ++nt){
      int pA0=(int)pk[0][nt][0], pA1=(int)pk[0][nt][1];
      int pB0=(int)pk[1][nt][0], pB1=(int)pk[1][nt][1];
      int a0 = __builtin_amdgcn_ds_bpermute(idxA, pA0);
      int b0 = __builtin_amdgcn_ds_bpermute(idxA, pB0);
      int a1 = __builtin_amdgcn_ds_bpermute(idxA, pA1);
      int b1 = __builtin_amdgcn_ds_bpermute(idxA, pB1);
      int a2r= __builtin_amdgcn_ds_bpermute(idxB, pA0);
      int b2 = __builtin_amdgcn_ds_bpermute(idxB, pB0);
      int a3 = __builtin_amdgcn_ds_bpermute(idxB, pA1);
      int b3 = __builtin_amdgcn_ds_bpermute(idxB, pB1);
      union{ int ii[4]; bf16x8 v; } u;
      u.ii[0] = lo32 ? a0 : b0;
      u.ii[1] = lo32 ? a1 : b1;
      u.ii[2] = lo32 ? a2r: b2;
      u.ii[3] = lo32 ? a3 : b3;
      a2[nt] = u.v;
    }
    __builtin_amdgcn_s_setprio(1);
    #pragma unroll
    for (int nt2=0; nt2<8; ++nt2){
      bf16x8 bf = *(const bf16x8*)(W2 + nt2*512 + l*8);
      accY[0][nt2] = MFMA16(a2[0], bf, accY[0][nt2]);
      accY[1][nt2] = MFMA16(a2[1], bf, accY[1][nt2]);
    }
    __builtin_amdgcn_s_setprio(0);

    __builtin_amdgcn_s_barrier();                 // release buf bc for restage
    __builtin_amdgcn_sched_barrier(0);
    bc = (bc==2) ? 0 : bc+1;
    bs = (bs==2) ? 0 : bs+1;
  }

  // epilogue: bounce accY through ws (per-wave 32x132 slab), b128 yt stores.
  unsigned short* wse = ws + wv*4224;
  #pragma unroll
  for (int mt2=0; mt2<2; ++mt2)
    #pragma unroll
    for (int nt2=0; nt2<8; ++nt2){
      f32x4 v = accY[mt2][nt2];
      unsigned p01 = cvtpk(v.x, v.y), p23 = cvtpk(v.z, v.w);
      int o = nt2*16 + i, rowb = mt2*16 + q*4;
      wse[(rowb+0)*132 + o] = (unsigned short)(p01 & 0xffffu);
      wse[(rowb+1)*132 + o] = (unsigned short)(p01 >> 16);
      wse[(rowb+2)*132 + o] = (unsigned short)(p23 & 0xffffu);
      wse[(rowb+3)*132 + o] = (unsigned short)(p23 >> 16);
    }
  asm volatile("s_waitcnt lgkmcnt(0)" ::: "memory");
  __builtin_amdgcn_sched_barrier(0);
  unsigned short* yp = yt + (size_t)t*XT_PLANE + (size_t)(r0 + wv*32)*128;
  #pragma unroll
  for (int u=0; u<8; ++u){
    int row = u*4 + (l>>4);
    int o8  = (l&15)*8;
    bf16x8 vv = *(const bf16x8*)(wse + row*132 + o8);
    *(bf16x8*)(yp + row*128 + o8) = vv;
  }
}

// ---------------- output: yt[t][r][o] -> out[r][o*16+t] fp32 ----------------
__global__ __launch_bounds__(256) void k_out(const unsigned short* __restrict__ yt,
                                             float* __restrict__ out){
  __shared__ unsigned short ls[16384];            // 8r x 8og x 16t x 16o'
  const int r0 = blockIdx.x*8;
  const int tid = threadIdx.x;
  { // ph1
    const int tp = tid>>4, cg = tid&15;
    const int og = cg>>1, o0 = (cg&1)*8;
    #pragma unroll
    for (int r=0; r<8; ++r){
      bf16x8 v = *(const bf16x8*)(yt + (size_t)tp*XT_PLANE
                                     + (size_t)(r0+r)*128 + cg*8);
      *(bf16x8*)(ls + r*2048 + og*256 + tp*16 + o0) = v;
    }
  }
  __syncthreads();
  const int wv = tid>>6, l = tid&63, g = l>>4, i = l&15;
  unsigned base = lds_off(ls) + (unsigned)wv*8192u + (unsigned)l*8u;
  #pragma unroll
  for (int rr=0; rr<2; ++rr){
    unsigned long long d0,d1,d2,d3,d4,d5,d6,d7;
    if (rr==0){
      TRRD(d0, base, "0");    TRRD(d1, base, "512");
      TRRD(d2, base, "1024"); TRRD(d3, base, "1536");
      TRRD(d4, base, "2048"); TRRD(d5, base, "2560");
      TRRD(d6, base, "3072"); TRRD(d7, base, "3584");
    } else {
      TRRD(d0, base, "4096"); TRRD(d1, base, "4608");
      TRRD(d2, base, "5120"); TRRD(d3, base, "5632");
      TRRD(d4, base, "6144"); TRRD(d5, base, "6656");
      TRRD(d6, base, "7168"); TRRD(d7, base, "7680");
    }
    asm volatile("s_waitcnt lgkmcnt(0)" ::: "memory");
    __builtin_amdgcn_sched_barrier(0);
    float* op = out + (size_t)(r0 + 2*wv + rr)*2048 + i*16 + g*4;
    unsigned long long dd[8] = {d0,d1,d2,d3,d4,d5,d6,d7};
    #pragma unroll
    for (int og=0; og<8; ++og){
      union{ unsigned long long u; unsigned short s[4]; } w; w.u = dd[og];
      f32x4 o4;
      o4.x = bfs(w.s[0]); o4.y = bfs(w.s[1]);
      o4.z = bfs(w.s[2]); o4.w = bfs(w.s[3]);
      *(f32x4*)(op + og*256) = o4;
    }
  }
}

// ---------------- exact fp32 fallback (if ws too small) ---------------------
__global__ __launch_bounds__(128) void k_naive(const float* __restrict__ x,
                                               const float* __restrict__ w1,
                                               const float* __restrict__ w2,
                                               float* __restrict__ out){
  int bid = blockIdx.x; int t = bid & 15; int row = bid >> 4;
  int tid = threadIdx.x;
  __shared__ float xsm[128]; __shared__ float hsm[512];
  xsm[tid] = x[(size_t)row*2048 + tid*16 + t];
  __syncthreads();
  for (int kk=0; kk<4; ++kk){
    int o = kk*128 + tid; float a = 0.f;
    for (int c=0;c<128;++c) a += xsm[c]*w1[(o*128+c)*16+t];
    hsm[o] = 0.5f*a*(1.0f+erff(a*0.70710678f));
  }
  __syncthreads();
  float a = 0.f;
  for (int cf=0; cf<512; ++cf) a += hsm[cf]*w2[(tid*512+cf)*16+t];
  out[(size_t)row*2048 + tid*16 + t] = a;
}

// ---------------------------------------------------------------------------
extern "C" void kernel_launch(void* const* d_in, const int* in_sizes, int n_in,
                              void* d_out, int out_size, void* d_ws, size_t ws_size,
                              hipStream_t stream){
  const float* x  = (const float*)d_in[0];
  const float* w1 = (const float*)d_in[1];
  const float* w2 = (const float*)d_in[2];
  float* out = (float*)d_out;

  const size_t NEEDED = 71303168ULL; // 67 MB xt/yt + 2+2 MB packed weights
  if (ws_size < NEEDED || d_ws == nullptr){
    k_naive<<<dim3(16384*16), dim3(128), 0, stream>>>(x, w1, w2, out);
    return;
  }
  unsigned short* xt  = (unsigned short*)d_ws;    // doubles as yt (in-place)
  unsigned short* w1p = xt + 33554432;
  unsigned short* w2p = w1p + 1048576;

  k_packw<<<dim3(1024), dim3(256), 0, stream>>>(w1, w2, w1p, w2p);
  k_xt  <<<dim3(2048), dim3(256), 0, stream>>>(x, xt);
  k_ffn <<<dim3(2048), dim3(256), 0, stream>>>(xt, w1p, w2p, xt);
  k_out <<<dim3(2048), dim3(256), 0, stream>>>(xt, out);
}